// Round 6
// baseline (236.649 us; speedup 1.0000x reference)
//
#include <hip/hip_runtime.h>
#include <hip/hip_bf16.h>
#include <math.h>

#define B_   4
#define T_   4096
#define DIN_ 1024
#define H_   16
#define D_   64
#define M_   (B_*T_)      // 16384
#define N_   (H_*D_*2)    // 2048
#define K_   DIN_         // 1024
#define C_   64           // scan chunks per (b,h) chain
#define CL_  (T_/C_)      // 64 steps per chunk

typedef unsigned short u16;
typedef __attribute__((ext_vector_type(8))) short short8_t;
typedef __attribute__((ext_vector_type(16))) float f32x16;

__device__ __forceinline__ u16 f2bf(float f) {
  unsigned int x = __float_as_uint(f);
  x += 0x7fffu + ((x >> 16) & 1u);   // round-to-nearest-even (finite inputs)
  return (u16)(x >> 16);
}
__device__ __forceinline__ float bf2f(unsigned int u) {
  return __uint_as_float((u & 0xffffu) << 16);
}
__device__ __forceinline__ unsigned pk_bf16(float x, float y) {
  float2 f; f.x = x; f.y = y;
  union { __hip_bfloat162 h2; unsigned u; } c;
  c.h2 = __float22bfloat162_rn(f);
  return c.u;
}

// async global->LDS, 16 B per lane. LDS dest = wave-uniform base + lane*16.
__device__ __forceinline__ void g2l16(const u16* g, u16* l) {
  __builtin_amdgcn_global_load_lds(
      (const __attribute__((address_space(1))) void*)g,
      (__attribute__((address_space(3))) void*)l, 16, 0, 0);
}

// ---------------- prep: cast inputs (R6: dense loads) + cast-transpose weights ----------
__global__ __launch_bounds__(256)
void prep(const float* __restrict__ inputs, const float* __restrict__ kvk,
          u16* __restrict__ aB, u16* __restrict__ wBt) {
  __shared__ float tile[32][33];
  int bid = blockIdx.x;
  int tid = threadIdx.x;
  if (bid < 8192) {
    // two fully-dense passes over M*K/4 float4s (old version had stride-2 lanes)
    int j = bid * 256 + tid;            // 0..2097151
    const float4* s4 = (const float4*)inputs;
    float4 a = s4[j];
    float4 b = s4[j + 2097152];
    uint2 oa; oa.x = pk_bf16(a.x, a.y); oa.y = pk_bf16(a.z, a.w);
    uint2 ob; ob.x = pk_bf16(b.x, b.y); ob.y = pk_bf16(b.z, b.w);
    ((uint2*)aB)[j]           = oa;
    ((uint2*)aB)[j + 2097152] = ob;
  } else {
    int b2 = bid - 8192;              // 2048 blocks
    int kb = (b2 & 31) * 32;          // K/32 = 32
    int nb = (b2 >> 5) * 32;          // N/32 = 64
    int r  = tid >> 3;                // 0..31
    int c4 = (tid & 7) * 4;           // 0..28
    float4 v = *(const float4*)&kvk[(size_t)(kb + r) * N_ + nb + c4];
    tile[r][c4+0] = v.x; tile[r][c4+1] = v.y; tile[r][c4+2] = v.z; tile[r][c4+3] = v.w;
    __syncthreads();
    uint2 o;
    o.x = pk_bf16(tile[c4+0][r], tile[c4+1][r]);
    o.y = pk_bf16(tile[c4+2][r], tile[c4+3][r]);
    *(uint2*)&wBt[(size_t)(nb + r) * K_ + kb + c4] = o;
  }
}

// ---------------- gemm_kv R6: 256x256, 16 waves, 32x32x16 MFMA, reg-dbuf pipeline -------
// 1024 thr = 16 waves (4x4 of 64x64 tiles, 2x2 frags of 32x32). K-step = 16.
// LDS 4 parities x (A 8KB + B 8KB) = 64 KB; tile row = 16 u16 (32 B), so both
// g2l16 staging AND fragment ds_read_b128 are CONTIGUOUS 1KB wave accesses --
// conflict-free, no swizzle anywhere.
// Phase kt: { 4 ds_read(kt+1 -> other reg set)  [drains during MFMA]
//             1 g2l16 stage(kt+3 -> par (kt+3)&3)
//             4 MFMA(kt) on regs loaded LAST phase }  -> vmcnt(1) -> barrier.
// RAW: vmcnt(1) at end of phase kt leaves only stage(kt+3) outstanding =>
//   stage(kt+2) (issued phase kt-1) landed => phase kt+1 may ds_read par kt+2. ✓
// WAR: stage(kt+3) writes par (kt-1)&3, whose reads (for kt-1) were issued in
//   phase kt-2 and lgkm-consumed by MFMA(kt-1) in phase kt-1, i.e. before the
//   barrier that precedes this stage. Cross-wave safe via that barrier. ✓

#define FENCE asm volatile("" ::: "memory")
#define KBAR do { FENCE; __builtin_amdgcn_s_barrier(); FENCE; } while (0)

#define MFMA32(a,b,c) __builtin_amdgcn_mfma_f32_32x32x16_bf16(a,b,c,0,0,0)

#define LOADS(PN, AF, BF) do { \
  AF[0] = *(const short8_t*)&lds[(PN)*4096 + aOff      ]; \
  AF[1] = *(const short8_t*)&lds[(PN)*4096 + aOff + 512]; \
  BF[0] = *(const short8_t*)&lds[16384 + (PN)*4096 + bOff      ]; \
  BF[1] = *(const short8_t*)&lds[16384 + (PN)*4096 + bOff + 512]; \
} while (0)

#define MMAS(AF, BF) do { \
  __builtin_amdgcn_s_setprio(1); \
  acc[0][0] = MFMA32(AF[0], BF[0], acc[0][0]); \
  acc[0][1] = MFMA32(AF[0], BF[1], acc[0][1]); \
  acc[1][0] = MFMA32(AF[1], BF[0], acc[1][0]); \
  acc[1][1] = MFMA32(AF[1], BF[1], acc[1][1]); \
  __builtin_amdgcn_s_setprio(0); \
} while (0)

#define PHASE(KT, PN, PS, AFm, BFm, AFl, BFl) do { \
  LOADS(PN, AFl, BFl); \
  g2l16(gS + (size_t)((KT)+3)*16, lds + stBase + (PS)*4096); \
  MMAS(AFm, BFm); \
  asm volatile("s_waitcnt vmcnt(1)" ::: "memory"); \
  KBAR; \
} while (0)

__global__ __launch_bounds__(1024)
void gemm_kv(const u16* __restrict__ A, const u16* __restrict__ Bt,
             const float* __restrict__ q,
             float* __restrict__ pbuf, u16* __restrict__ vbuf,
             float* __restrict__ aggU, float* __restrict__ aggW) {
  extern __shared__ __align__(16) char smem[];
  u16* lds = (u16*)smem;

  const int tid  = threadIdx.x;
  const int wv   = tid >> 6;          // 0..15
  const int lane = tid & 63;
  const int l31  = lane & 31;
  const int hi   = lane >> 5;
  const int wr2  = wv >> 2;           // 0..3  (m: 64-row group)
  const int wc2  = wv & 3;            // 0..3  (n: 64-col group)

  // XCD-aware bijective swizzle (512 % 8 == 0)
  const int g  = blockIdx.x;
  const int wg = (g & 7) * 64 + (g >> 3);
  const int nt = wg & 7;              // heads {2nt, 2nt+1}
  const int mt = wg >> 3;             // rows [mt*256, +256)
  const int bm = mt * 256;
  const int bn = nt * 256;

  // staging: waves 0-7 stage A rows [wv*32,+32), waves 8-15 stage B likewise.
  // lane l covers row base + (l>>1), k-half l&1 (16 B each) -- matches linear
  // g2l16 dest (base + lane*16B) exactly.
  const int stBase = (wv < 8) ? wv * 512 : 16384 + (wv - 8) * 512;
  const u16* gS = (wv < 8)
    ? A  + (size_t)(bm + wv*32       + (lane >> 1)) * K_ + (lane & 1) * 8
    : Bt + (size_t)(bn + (wv-8)*32   + (lane >> 1)) * K_ + (lane & 1) * 8;

  // fragment ds_read bases (u16): A frag i: rows wr2*64+i*32+l31, k-half hi.
  const int aOff = (wr2*64 + l31) * 16 + hi * 8;           // + par*4096 + i*512
  const int bOff = (wc2*64 + l31) * 16 + hi * 8;           // + 16384 + par*4096 + j*512

  f32x16 acc[2][2] = {};
  short8_t af0[2], bf0[2], af1[2], bf1[2];

  // prologue: stage kt0,kt1,kt2; wait kt0+kt1; barrier; preload kt0 frags -> set0
  g2l16(gS,      lds + stBase + 0*4096);
  g2l16(gS + 16, lds + stBase + 1*4096);
  g2l16(gS + 32, lds + stBase + 2*4096);
  asm volatile("s_waitcnt vmcnt(1)" ::: "memory");
  KBAR;
  LOADS(0, af0, bf0);

  // main: kt = 0..55 (7 x 8 phases); every phase stages kt+3 (<= 58)
#pragma unroll 1
  for (int kq = 0; kq < 7; ++kq) {
    const int kt = kq * 8;
    PHASE(kt+0, 1, 3, af0, bf0, af1, bf1);
    PHASE(kt+1, 2, 0, af1, bf1, af0, bf0);
    PHASE(kt+2, 3, 1, af0, bf0, af1, bf1);
    PHASE(kt+3, 0, 2, af1, bf1, af0, bf0);
    PHASE(kt+4, 1, 3, af0, bf0, af1, bf1);
    PHASE(kt+5, 2, 0, af1, bf1, af0, bf0);
    PHASE(kt+6, 3, 1, af0, bf0, af1, bf1);
    PHASE(kt+7, 0, 2, af1, bf1, af0, bf0);
  }
  // tail kt = 56..63
  PHASE(56, 1, 3, af0, bf0, af1, bf1);   // stage 59
  PHASE(57, 2, 0, af1, bf1, af0, bf0);   // stage 60
  PHASE(58, 3, 1, af0, bf0, af1, bf1);   // stage 61
  PHASE(59, 0, 2, af1, bf1, af0, bf0);   // stage 62
  PHASE(60, 1, 3, af0, bf0, af1, bf1);   // stage 63
  {  // kt=61: read kt62 (par 2), no stage, drain
    LOADS(2, af0, bf0);
    MMAS(af1, bf1);
    asm volatile("s_waitcnt vmcnt(0)" ::: "memory");
    KBAR;
  }
  {  // kt=62: read kt63 (par 3)
    LOADS(3, af1, bf1);
    MMAS(af0, bf0);
    KBAR;
  }
  MMAS(af1, bf1);                        // kt=63

  // ---------------- fused epilogue (32x32 C/D layout) ----------------
  // C/D: col(n) = l31, row = (reg&3) + 8*(reg>>2) + 4*hi.
  // t = wr2*64 + i*32 + row;  n' = wc2*64 + j*32 + l31; head nh = wc2>>1,
  // col-half wc2p = wc2&1. parity(n') = parity(l31):
  //   odd l31 -> v column d = wc2p*32 + j*16 + (l31>>1)
  //   even l31 -> k column (dot with q, reduce over 16 even lanes per hi-half)
  u16*   vtile = (u16*)smem;                  // [2][256][72] u16 = 73728 B
  float* sred  = (float*)(smem + 73728);      // [2][256][5]  f32 = 10240 B (stride 5: bank-clean)
  float* pS    = (float*)(smem + 83968);      // [2][256]     f32 =  2048 B (end 86016)

  __syncthreads();   // waits own lgkm too -> all K-loop LDS reads complete

  const int nh   = wc2 >> 1;
  const int wc2p = wc2 & 1;

  float qv[2];
  qv[0] = q[(nt*2 + nh)*64 + wc2p*32 +  0 + (l31 >> 1)];
  qv[1] = q[(nt*2 + nh)*64 + wc2p*32 + 16 + (l31 >> 1)];

#pragma unroll
  for (int i = 0; i < 2; ++i) {
#pragma unroll
    for (int reg = 0; reg < 16; ++reg) {
      const int t = wr2*64 + i*32 + (reg & 3) + 8*(reg >> 2) + 4*hi;
      const float x0 = fmaxf(acc[i][0][reg], 0.f);
      const float x1 = fmaxf(acc[i][1][reg], 0.f);
      if (l31 & 1) {
        const int d0 = wc2p*32 + (l31 >> 1);
        vtile[(nh*256 + t)*72 + d0     ] = f2bf(x0);
        vtile[(nh*256 + t)*72 + d0 + 16] = f2bf(x1);
      } else {
        float ps = qv[0]*x0 + qv[1]*x1;
        ps += __shfl_xor(ps, 2);
        ps += __shfl_xor(ps, 4);
        ps += __shfl_xor(ps, 8);
        ps += __shfl_xor(ps, 16);
        if (l31 == 0)
          sred[(nh*256 + t)*5 + wc2p] = ps;
      }
    }
  }
  __syncthreads();

  const int b  = mt >> 4;             // 16 m-tiles per batch
  const int t0 = (mt & 15) * 256;
  if (tid < 512) {
    // p-phase: wave = one (hh, 64-t chunk); U via shuffle reduce
    const int hh = tid >> 8;
    const int t  = tid & 255;
    const float* sr = &sred[(hh*256 + t)*5];
    float s = sr[0] + sr[1];
    float p = __expf(fminf(fmaxf(s, -60.f), 60.f));
    pS[hh*256 + t] = p;
    pbuf[(size_t)(b*H_ + nt*2 + hh) * T_ + t0 + t] = p;
    float u = p;
#pragma unroll
    for (int off = 32; off; off >>= 1) u += __shfl_down(u, off);
    if (lane == 0)
      aggU[(b*H_ + nt*2 + hh)*C_ + (mt & 15)*4 + ((tid >> 6) & 3)] = u;
  }
  __syncthreads();

  if (l31 & 1) {
    // W straight from acc (odd lanes hold v columns). Wave's t-range is one
    // 64-t chunk (wr2); hi halves combined via xor-32 shuffle.
    float Wv0 = 0.f, Wv1 = 0.f;
#pragma unroll
    for (int i = 0; i < 2; ++i)
#pragma unroll
      for (int reg = 0; reg < 16; ++reg) {
        const int t = wr2*64 + i*32 + (reg & 3) + 8*(reg >> 2) + 4*hi;
        const float p = pS[nh*256 + t];
        Wv0 += p * fmaxf(acc[i][0][reg], 0.f);
        Wv1 += p * fmaxf(acc[i][1][reg], 0.f);
      }
    Wv0 += __shfl_xor(Wv0, 32);
    Wv1 += __shfl_xor(Wv1, 32);
    if (hi == 0) {
      const int blk = (b*H_ + nt*2 + nh)*C_ + (mt & 15)*4 + wr2;
      aggW[(size_t)blk * D_ + wc2p*32 +  0 + (l31 >> 1)] = Wv0;
      aggW[(size_t)blk * D_ + wc2p*32 + 16 + (l31 >> 1)] = Wv1;
    }
  }
  {
    // coalesced v store: 512 rows x 128 B (vbuf flat [bh][t][d])
    const int d0 = (tid & 7) * 8;
#pragma unroll
    for (int k2 = 0; k2 < 4; ++k2) {
      const int row = (tid >> 3) + 128*k2;   // 0..511
      const int hh  = row >> 8;
      const int t   = row & 255;
      uint4 val = *(const uint4*)&vtile[(hh*256 + t)*72 + d0];
      *(uint4*)&vbuf[((size_t)(b*H_ + nt*2 + hh) * T_ + t0 + t) * D_ + d0] = val;
    }
  }
}

// ---------------- pass 3: additive prefix + seeded scan + h-reduction (unchanged) ------
__global__ __launch_bounds__(1024)
void scan_pass3(const u16* __restrict__ vbuf, const float* __restrict__ pbuf,
                const float* __restrict__ aggU, const float* __restrict__ aggW,
                float* __restrict__ out) {
  __shared__ float pS[H_][CL_];         // 4 KB
  __shared__ float wbuf[H_][8][D_ + 1]; // 33.3 KB
  int bc = blockIdx.x;
  int b  = bc >> 6;
  int c  = bc & (C_ - 1);
  int tid  = threadIdx.x;
  int h    = tid >> 6;
  int lane = tid & 63;
  int bh   = b * H_ + h;
  int t0   = c * CL_;

  pS[h][lane] = pbuf[(size_t)bh * T_ + t0 + lane];

  // additive exclusive prefix over chunks [0,c): independent loads, pipelines freely
  float U = 0.f, W = 0.f;
  for (int j = 0; j < c; ++j) {
    int idx = bh * C_ + j;
    U += aggU[idx];
    W += aggW[(size_t)idx * D_ + lane];
  }
  __syncthreads();

  const u16* vp = vbuf + ((size_t)bh * T_ + t0) * D_ + lane;
  for (int gg = 0; gg < 8; ++gg) {
#pragma unroll
    for (int ii = 0; ii < 8; ++ii) {
      int i = gg * 8 + ii;
      float p = pS[h][i];
      float v = bf2f(vp[i * D_]);
      U += p;
      W += p * v;
      wbuf[h][ii][lane] = __fdividef(W, U);
    }
    __syncthreads();
    if (tid < 512) {
      int ii = tid >> 6, dd = tid & 63;
      float acc = 0.f;
#pragma unroll
      for (int hh = 0; hh < H_; ++hh) acc += wbuf[hh][ii][dd];
      out[((size_t)b * T_ + t0 + gg*8 + ii) * D_ + dd] = acc;
    }
    __syncthreads();
  }
}

extern "C" void kernel_launch(void* const* d_in, const int* in_sizes, int n_in,
                              void* d_out, int out_size, void* d_ws, size_t ws_size,
                              hipStream_t stream) {
  const float* inputs = (const float*)d_in[0];   // (B,T,DIN)
  const float* kvk    = (const float*)d_in[1];   // (DIN,H,D,2)
  const float* qk     = (const float*)d_in[2];   // (H,D)
  float* out = (float*)d_out;
  char* ws = (char*)d_ws;

  u16*   aB   = (u16*)ws;                       // 33,554,432 B  inputs bf16 [M][K]
  u16*   wBt  = (u16*)(ws + 33554432);          //  4,194,304 B  weights bf16 [N][K]
  u16*   vb   = (u16*)(ws + 37748736);          // 33,554,432 B  v bf16 [b,h,t,d]
  float* pb   = (float*)(ws + 71303168);        //  1,048,576 B  p=exp(s) [b,h,t]
  float* aggU = (float*)(ws + 72351744);        //     16,384 B
  float* aggW = (float*)(ws + 72368128);        //  1,048,576 B  (ends ~73.4 MB)

  prep<<<10240, 256, 0, stream>>>(inputs, kvk, aB, wBt);
  gemm_kv<<<512, 1024, 86016, stream>>>(aB, wBt, qk, pb, vb, aggU, aggW);
  scan_pass3<<<B_*C_, 1024, 0, stream>>>(vb, pb, aggU, aggW, out);
}

// Round 7
// 235.425 us; speedup vs baseline: 1.0052x; 1.0052x over previous
//
#include <hip/hip_runtime.h>
#include <hip/hip_bf16.h>
#include <math.h>

#define B_   4
#define T_   4096
#define DIN_ 1024
#define H_   16
#define D_   64
#define M_   (B_*T_)      // 16384
#define N_   (H_*D_*2)    // 2048
#define K_   DIN_         // 1024
#define C_   64           // scan chunks per (b,h) chain
#define CL_  (T_/C_)      // 64 steps per chunk

typedef unsigned short u16;
typedef __attribute__((ext_vector_type(8))) short short8_t;
typedef __attribute__((ext_vector_type(16))) float f32x16;

__device__ __forceinline__ u16 f2bf(float f) {
  unsigned int x = __float_as_uint(f);
  x += 0x7fffu + ((x >> 16) & 1u);   // round-to-nearest-even (finite inputs)
  return (u16)(x >> 16);
}
__device__ __forceinline__ float bf2f(unsigned int u) {
  return __uint_as_float((u & 0xffffu) << 16);
}
__device__ __forceinline__ unsigned pk_bf16(float x, float y) {
  float2 f; f.x = x; f.y = y;
  union { __hip_bfloat162 h2; unsigned u; } c;
  c.h2 = __float22bfloat162_rn(f);
  return c.u;
}

// async global->LDS, 16 B per lane. LDS dest = wave-uniform base + lane*16.
__device__ __forceinline__ void g2l16(const u16* g, u16* l) {
  __builtin_amdgcn_global_load_lds(
      (const __attribute__((address_space(1))) void*)g,
      (__attribute__((address_space(3))) void*)l, 16, 0, 0);
}

// ---------------- prep: cast inputs (dense loads) + cast-transpose weights -------------
__global__ __launch_bounds__(256)
void prep(const float* __restrict__ inputs, const float* __restrict__ kvk,
          u16* __restrict__ aB, u16* __restrict__ wBt) {
  __shared__ float tile[32][33];
  int bid = blockIdx.x;
  int tid = threadIdx.x;
  if (bid < 8192) {
    // two fully-dense passes over M*K/4 float4s
    int j = bid * 256 + tid;            // 0..2097151
    const float4* s4 = (const float4*)inputs;
    float4 a = s4[j];
    float4 b = s4[j + 2097152];
    uint2 oa; oa.x = pk_bf16(a.x, a.y); oa.y = pk_bf16(a.z, a.w);
    uint2 ob; ob.x = pk_bf16(b.x, b.y); ob.y = pk_bf16(b.z, b.w);
    ((uint2*)aB)[j]           = oa;
    ((uint2*)aB)[j + 2097152] = ob;
  } else {
    int b2 = bid - 8192;              // 2048 blocks
    int kb = (b2 & 31) * 32;          // K/32 = 32
    int nb = (b2 >> 5) * 32;          // N/32 = 64
    int r  = tid >> 3;                // 0..31
    int c4 = (tid & 7) * 4;           // 0..28
    float4 v = *(const float4*)&kvk[(size_t)(kb + r) * N_ + nb + c4];
    tile[r][c4+0] = v.x; tile[r][c4+1] = v.y; tile[r][c4+2] = v.z; tile[r][c4+3] = v.w;
    __syncthreads();
    uint2 o;
    o.x = pk_bf16(tile[c4+0][r], tile[c4+1][r]);
    o.y = pk_bf16(tile[c4+2][r], tile[c4+3][r]);
    *(uint2*)&wBt[(size_t)(nb + r) * K_ + kb + c4] = o;
  }
}

// ---------------- gemm_kv R7: R6 pipeline + FRAGMENT-MAJOR LDS (conflict-free) ----------
// 1024 thr = 16 waves (4x4 of 64x64 tiles, 2x2 frags of 32x32). K-step = 16.
// LDS 4 parities x (A 8KB + B 8KB) = 64 KB.
// Layout (R7 fix): each 32-row x K16 subtile (1 KB) is stored FRAGMENT-MAJOR:
//   granule g (16 B) holds (row = g&31, khalf = g>>5).
// => fragment ds_read_b128: addr = subtile_base + lane*16B  -- contiguous 1 KB
//    wave access, ZERO bank conflicts (R6's row-major had 8-way: 32B row
//    stride put all lanes in banks {0,8,16,24}).
// => staging source permuted to match (both-sides rule): lane l fetches
//    row l&31, khalf l>>5; g2l16 linear dest unchanged.
// Phase kt: { 4 ds_read(kt+1 -> other reg set)  [drains during MFMA]
//             1 g2l16 stage(kt+3 -> par (kt+3)&3)
//             4 MFMA(kt) on regs loaded LAST phase }  -> vmcnt(1) -> barrier.
// RAW: vmcnt(1) at end of phase kt leaves only stage(kt+3) outstanding =>
//   stage(kt+2) landed => phase kt+1 may ds_read par kt+2. ✓
// WAR: stage(kt+3) overwrites par (kt-1)&3, whose reads were lgkm-consumed by
//   MFMA(kt-1) before the previous barrier. ✓

#define FENCE asm volatile("" ::: "memory")
#define KBAR do { FENCE; __builtin_amdgcn_s_barrier(); FENCE; } while (0)

#define MFMA32(a,b,c) __builtin_amdgcn_mfma_f32_32x32x16_bf16(a,b,c,0,0,0)

#define LOADS(PN, AF, BF) do { \
  AF[0] = *(const short8_t*)&lds[(PN)*4096 + aOff      ]; \
  AF[1] = *(const short8_t*)&lds[(PN)*4096 + aOff + 512]; \
  BF[0] = *(const short8_t*)&lds[16384 + (PN)*4096 + bOff      ]; \
  BF[1] = *(const short8_t*)&lds[16384 + (PN)*4096 + bOff + 512]; \
} while (0)

#define MMAS(AF, BF) do { \
  __builtin_amdgcn_s_setprio(1); \
  acc[0][0] = MFMA32(AF[0], BF[0], acc[0][0]); \
  acc[0][1] = MFMA32(AF[0], BF[1], acc[0][1]); \
  acc[1][0] = MFMA32(AF[1], BF[0], acc[1][0]); \
  acc[1][1] = MFMA32(AF[1], BF[1], acc[1][1]); \
  __builtin_amdgcn_s_setprio(0); \
} while (0)

#define PHASE(KT, PN, PS, AFm, BFm, AFl, BFl) do { \
  LOADS(PN, AFl, BFl); \
  g2l16(gS + (size_t)((KT)+3)*16, lds + stBase + (PS)*4096); \
  MMAS(AFm, BFm); \
  asm volatile("s_waitcnt vmcnt(1)" ::: "memory"); \
  KBAR; \
} while (0)

__global__ __launch_bounds__(1024)
void gemm_kv(const u16* __restrict__ A, const u16* __restrict__ Bt,
             const float* __restrict__ q,
             float* __restrict__ pbuf, u16* __restrict__ vbuf,
             float* __restrict__ aggU, float* __restrict__ aggW) {
  extern __shared__ __align__(16) char smem[];
  u16* lds = (u16*)smem;

  const int tid  = threadIdx.x;
  const int wv   = tid >> 6;          // 0..15
  const int lane = tid & 63;
  const int l31  = lane & 31;
  const int hi   = lane >> 5;
  const int wr2  = wv >> 2;           // 0..3  (m: 64-row group)
  const int wc2  = wv & 3;            // 0..3  (n: 64-col group)

  // XCD-aware bijective swizzle (512 % 8 == 0)
  const int g  = blockIdx.x;
  const int wg = (g & 7) * 64 + (g >> 3);
  const int nt = wg & 7;              // heads {2nt, 2nt+1}
  const int mt = wg >> 3;             // rows [mt*256, +256)
  const int bm = mt * 256;
  const int bn = nt * 256;

  // staging: waves 0-7 stage A rows [wv*32,+32), waves 8-15 stage B likewise.
  // fragment-major source permutation: lane l loads row l&31, khalf l>>5.
  const int stBase = (wv < 8) ? wv * 512 : 16384 + (wv - 8) * 512;
  const u16* gS = (wv < 8)
    ? A  + (size_t)(bm + wv*32     + l31) * K_ + hi * 8
    : Bt + (size_t)(bn + (wv-8)*32 + l31) * K_ + hi * 8;

  // fragment ds_read bases (u16): subtile (wr2*2+i) at (wr2*2+i)*512, +lane*8
  const int aOff = wr2 * 1024 + lane * 8;            // + par*4096 + i*512
  const int bOff = wc2 * 1024 + lane * 8;            // + 16384 + par*4096 + j*512

  f32x16 acc[2][2] = {};
  short8_t af0[2], bf0[2], af1[2], bf1[2];

  // prologue: stage kt0,kt1,kt2; wait kt0+kt1; barrier; preload kt0 frags -> set0
  g2l16(gS,      lds + stBase + 0*4096);
  g2l16(gS + 16, lds + stBase + 1*4096);
  g2l16(gS + 32, lds + stBase + 2*4096);
  asm volatile("s_waitcnt vmcnt(1)" ::: "memory");
  KBAR;
  LOADS(0, af0, bf0);

  // main: kt = 0..55 (7 x 8 phases); every phase stages kt+3 (<= 58)
#pragma unroll 1
  for (int kq = 0; kq < 7; ++kq) {
    const int kt = kq * 8;
    PHASE(kt+0, 1, 3, af0, bf0, af1, bf1);
    PHASE(kt+1, 2, 0, af1, bf1, af0, bf0);
    PHASE(kt+2, 3, 1, af0, bf0, af1, bf1);
    PHASE(kt+3, 0, 2, af1, bf1, af0, bf0);
    PHASE(kt+4, 1, 3, af0, bf0, af1, bf1);
    PHASE(kt+5, 2, 0, af1, bf1, af0, bf0);
    PHASE(kt+6, 3, 1, af0, bf0, af1, bf1);
    PHASE(kt+7, 0, 2, af1, bf1, af0, bf0);
  }
  // tail kt = 56..63
  PHASE(56, 1, 3, af0, bf0, af1, bf1);   // stage 59
  PHASE(57, 2, 0, af1, bf1, af0, bf0);   // stage 60
  PHASE(58, 3, 1, af0, bf0, af1, bf1);   // stage 61
  PHASE(59, 0, 2, af1, bf1, af0, bf0);   // stage 62
  PHASE(60, 1, 3, af0, bf0, af1, bf1);   // stage 63
  {  // kt=61: read kt62 (par 2), no stage, drain
    LOADS(2, af0, bf0);
    MMAS(af1, bf1);
    asm volatile("s_waitcnt vmcnt(0)" ::: "memory");
    KBAR;
  }
  {  // kt=62: read kt63 (par 3)
    LOADS(3, af1, bf1);
    MMAS(af0, bf0);
    KBAR;
  }
  MMAS(af1, bf1);                        // kt=63

  // ---------------- fused epilogue (32x32 C/D layout) ----------------
  // C/D: col(n) = l31, row = (reg&3) + 8*(reg>>2) + 4*hi.
  // t = wr2*64 + i*32 + row;  n' = wc2*64 + j*32 + l31; head nh = wc2>>1,
  // col-half wc2p = wc2&1. parity(n') = parity(l31):
  //   odd l31 -> v column d = wc2p*32 + j*16 + (l31>>1)
  //   even l31 -> k column (dot with q, reduce over 16 even lanes per hi-half)
  u16*   vtile = (u16*)smem;                  // [2][256][72] u16 = 73728 B
  float* sred  = (float*)(smem + 73728);      // [2][256][5]  f32 = 10240 B
  float* pS    = (float*)(smem + 83968);      // [2][256]     f32 =  2048 B (end 86016)

  __syncthreads();   // all K-loop LDS reads complete before overlay writes

  const int nh   = wc2 >> 1;
  const int wc2p = wc2 & 1;

  float qv[2];
  qv[0] = q[(nt*2 + nh)*64 + wc2p*32 +  0 + (l31 >> 1)];
  qv[1] = q[(nt*2 + nh)*64 + wc2p*32 + 16 + (l31 >> 1)];

#pragma unroll
  for (int i = 0; i < 2; ++i) {
#pragma unroll
    for (int reg = 0; reg < 16; ++reg) {
      const int t = wr2*64 + i*32 + (reg & 3) + 8*(reg >> 2) + 4*hi;
      const float x0 = fmaxf(acc[i][0][reg], 0.f);
      const float x1 = fmaxf(acc[i][1][reg], 0.f);
      if (l31 & 1) {
        const int d0 = wc2p*32 + (l31 >> 1);
        vtile[(nh*256 + t)*72 + d0     ] = f2bf(x0);
        vtile[(nh*256 + t)*72 + d0 + 16] = f2bf(x1);
      } else {
        float ps = qv[0]*x0 + qv[1]*x1;
        ps += __shfl_xor(ps, 2);
        ps += __shfl_xor(ps, 4);
        ps += __shfl_xor(ps, 8);
        ps += __shfl_xor(ps, 16);
        if (l31 == 0)
          sred[(nh*256 + t)*5 + wc2p] = ps;
      }
    }
  }
  __syncthreads();

  const int b  = mt >> 4;             // 16 m-tiles per batch
  const int t0 = (mt & 15) * 256;
  if (tid < 512) {
    // p-phase: wave = one (hh, 64-t chunk); U via shuffle reduce
    const int hh = tid >> 8;
    const int t  = tid & 255;
    const float* sr = &sred[(hh*256 + t)*5];
    float s = sr[0] + sr[1];
    float p = __expf(fminf(fmaxf(s, -60.f), 60.f));
    pS[hh*256 + t] = p;
    pbuf[(size_t)(b*H_ + nt*2 + hh) * T_ + t0 + t] = p;
    float u = p;
#pragma unroll
    for (int off = 32; off; off >>= 1) u += __shfl_down(u, off);
    if (lane == 0)
      aggU[(b*H_ + nt*2 + hh)*C_ + (mt & 15)*4 + ((tid >> 6) & 3)] = u;
  }
  __syncthreads();

  if (l31 & 1) {
    // W straight from acc (odd lanes hold v columns). Wave's t-range is one
    // 64-t chunk (wr2); hi halves combined via xor-32 shuffle.
    float Wv0 = 0.f, Wv1 = 0.f;
#pragma unroll
    for (int i = 0; i < 2; ++i)
#pragma unroll
      for (int reg = 0; reg < 16; ++reg) {
        const int t = wr2*64 + i*32 + (reg & 3) + 8*(reg >> 2) + 4*hi;
        const float p = pS[nh*256 + t];
        Wv0 += p * fmaxf(acc[i][0][reg], 0.f);
        Wv1 += p * fmaxf(acc[i][1][reg], 0.f);
      }
    Wv0 += __shfl_xor(Wv0, 32);
    Wv1 += __shfl_xor(Wv1, 32);
    if (hi == 0) {
      const int blk = (b*H_ + nt*2 + nh)*C_ + (mt & 15)*4 + wr2;
      aggW[(size_t)blk * D_ + wc2p*32 +  0 + (l31 >> 1)] = Wv0;
      aggW[(size_t)blk * D_ + wc2p*32 + 16 + (l31 >> 1)] = Wv1;
    }
  }
  {
    // coalesced v store: 512 rows x 128 B (vbuf flat [bh][t][d])
    const int d0 = (tid & 7) * 8;
#pragma unroll
    for (int k2 = 0; k2 < 4; ++k2) {
      const int row = (tid >> 3) + 128*k2;   // 0..511
      const int hh  = row >> 8;
      const int t   = row & 255;
      uint4 val = *(const uint4*)&vtile[(hh*256 + t)*72 + d0];
      *(uint4*)&vbuf[((size_t)(b*H_ + nt*2 + hh) * T_ + t0 + t) * D_ + d0] = val;
    }
  }
}

// ---------------- pass 3: additive prefix + seeded scan + h-reduction (unchanged) ------
__global__ __launch_bounds__(1024)
void scan_pass3(const u16* __restrict__ vbuf, const float* __restrict__ pbuf,
                const float* __restrict__ aggU, const float* __restrict__ aggW,
                float* __restrict__ out) {
  __shared__ float pS[H_][CL_];         // 4 KB
  __shared__ float wbuf[H_][8][D_ + 1]; // 33.3 KB
  int bc = blockIdx.x;
  int b  = bc >> 6;
  int c  = bc & (C_ - 1);
  int tid  = threadIdx.x;
  int h    = tid >> 6;
  int lane = tid & 63;
  int bh   = b * H_ + h;
  int t0   = c * CL_;

  pS[h][lane] = pbuf[(size_t)bh * T_ + t0 + lane];

  // additive exclusive prefix over chunks [0,c): independent loads, pipelines freely
  float U = 0.f, W = 0.f;
  for (int j = 0; j < c; ++j) {
    int idx = bh * C_ + j;
    U += aggU[idx];
    W += aggW[(size_t)idx * D_ + lane];
  }
  __syncthreads();

  const u16* vp = vbuf + ((size_t)bh * T_ + t0) * D_ + lane;
  for (int gg = 0; gg < 8; ++gg) {
#pragma unroll
    for (int ii = 0; ii < 8; ++ii) {
      int i = gg * 8 + ii;
      float p = pS[h][i];
      float v = bf2f(vp[i * D_]);
      U += p;
      W += p * v;
      wbuf[h][ii][lane] = __fdividef(W, U);
    }
    __syncthreads();
    if (tid < 512) {
      int ii = tid >> 6, dd = tid & 63;
      float acc = 0.f;
#pragma unroll
      for (int hh = 0; hh < H_; ++hh) acc += wbuf[hh][ii][dd];
      out[((size_t)b * T_ + t0 + gg*8 + ii) * D_ + dd] = acc;
    }
    __syncthreads();
  }
}

extern "C" void kernel_launch(void* const* d_in, const int* in_sizes, int n_in,
                              void* d_out, int out_size, void* d_ws, size_t ws_size,
                              hipStream_t stream) {
  const float* inputs = (const float*)d_in[0];   // (B,T,DIN)
  const float* kvk    = (const float*)d_in[1];   // (DIN,H,D,2)
  const float* qk     = (const float*)d_in[2];   // (H,D)
  float* out = (float*)d_out;
  char* ws = (char*)d_ws;

  u16*   aB   = (u16*)ws;                       // 33,554,432 B  inputs bf16 [M][K]
  u16*   wBt  = (u16*)(ws + 33554432);          //  4,194,304 B  weights bf16 [N][K]
  u16*   vb   = (u16*)(ws + 37748736);          // 33,554,432 B  v bf16 [b,h,t,d]
  float* pb   = (float*)(ws + 71303168);        //  1,048,576 B  p=exp(s) [b,h,t]
  float* aggU = (float*)(ws + 72351744);        //     16,384 B
  float* aggW = (float*)(ws + 72368128);        //  1,048,576 B  (ends ~73.4 MB)

  prep<<<10240, 256, 0, stream>>>(inputs, kvk, aB, wBt);
  gemm_kv<<<512, 1024, 86016, stream>>>(aB, wBt, qk, pb, vb, aggU, aggW);
  scan_pass3<<<B_*C_, 1024, 0, stream>>>(vb, pb, aggU, aggW, out);
}